// Round 5
// baseline (351.735 us; speedup 1.0000x reference)
//
#include <hip/hip_runtime.h>
#include <hip/hip_bf16.h>

typedef __bf16 bf16x8 __attribute__((ext_vector_type(8)));
typedef float  f32x4  __attribute__((ext_vector_type(4)));

// LDS layout (bytes). Activations: 52 rows x 128 bf16, XOR-swizzled 16B k-blocks.
#define W_OFF 0            // weight chunk: 128n x 128k bf16, swizzled   (32768 B)
#define A_OFF 32768        // act buf A (13312 B)
#define B_OFF 46080        // act buf B (13312 B)
#define X_OFF 59392        // act buf X (13312 B)
#define SMALL 72704        // small persistent arrays (~4 KB)
#define SMEM_TOTAL 76736
#define WCHUNK 16384       // bf16 elems per weight chunk in global

// ws layout (bytes): wprep | Pi | Pt | Pr | Pu | Pu2   (~62.2 MB total)
#define WS_WPREP 0
#define WS_PI    196608
#define WS_PT    (WS_PI + 51200000)     // Pi: 100000*128 fp32
#define WS_PR    (WS_PT + 512000)       // Pt: 1000*128 fp32
#define WS_PU    (WS_PR + 3072)        // Pr: 6*128 fp32
#define WS_PU2   (WS_PU + 5120000)      // Pu: 10000*128 fp32

// ---------------- prep: fp32 [k][n] -> bf16 [chunk][n][swizzled k] ----------------
// chunks: 0-2 ne_w (item/rating/time K-slices), 3 ne1_w, 4 att1_w[:128] (x part), 5 att2_w
__global__ void prep_weights_kernel(const float* __restrict__ ne_w,
                                    const float* __restrict__ ne1_w,
                                    const float* __restrict__ att1_w,
                                    const float* __restrict__ att2_w,
                                    __hip_bfloat16* __restrict__ wout) {
  __shared__ float tile[64][65];
  const int bx = blockIdx.x;
  const int c = bx >> 2, kt = (bx >> 1) & 1, ntile = bx & 1;
  const float* src; int koff;
  if      (c < 3)  { src = ne_w;   koff = c * 128; }
  else if (c == 3) { src = ne1_w;  koff = 0; }
  else if (c == 4) { src = att1_w; koff = 0; }
  else             { src = att2_w; koff = 0; }
  const int tx = threadIdx.x, ty = threadIdx.y;
#pragma unroll
  for (int r = 0; r < 16; ++r) {
    int k = kt * 64 + r * 4 + ty, n = ntile * 64 + tx;
    tile[r * 4 + ty][tx] = src[(koff + k) * 128 + n];   // coalesced over n
  }
  __syncthreads();
#pragma unroll
  for (int r = 0; r < 16; ++r) {
    int n = ntile * 64 + r * 4 + ty, k = kt * 64 + tx;  // chunk-local k in [0,128)
    int off = (c * 128 + n) * 128 + (((k >> 3) ^ (n & 15)) << 3) + (k & 7);
    wout[off] = __float2bfloat16(tile[tx][r * 4 + ty]);
  }
}

// ---------------- helpers ----------------
__device__ __forceinline__ unsigned short bf_bits(float x) {
  return __builtin_bit_cast(unsigned short, __float2bfloat16(x));
}

// A from swizzled act buffer, B from swizzled LDS weight chunk; wave tile 16m x 64n
__device__ __forceinline__ void mfma_chunk(const __hip_bfloat16* sIn,
                                           const __hip_bfloat16* sWl,
                                           f32x4 acc[4], int m16, int nh, int lane) {
  const int mr = lane & 15;
  const int kq = lane >> 4;            // 0..3
  const int arow = (m16 * 16 + mr) * 128;
#pragma unroll
  for (int ks = 0; ks < 4; ++ks) {
    const int swz = (((ks * 4 + kq) ^ mr) << 3);
    bf16x8 a = *(const bf16x8*)(sIn + arow + swz);
#pragma unroll
    for (int nt = 0; nt < 4; ++nt) {
      const int n = nh * 64 + nt * 16 + mr;   // n&15 == mr -> same swz as A
      bf16x8 b = *(const bf16x8*)(sWl + n * 128 + swz);
      acc[nt] = __builtin_amdgcn_mfma_f32_16x16x32_bf16(a, b, acc[nt], 0, 0, 0);
    }
  }
}

// bias + optional row-vector + relu + swizzled bf16 store (rows < 50 only)
__device__ __forceinline__ void epilogue(f32x4 acc[4], const float* __restrict__ bias,
                                         const float* addvec, __hip_bfloat16* sOut,
                                         int m16, int nh, int lane) {
  const int mr = lane & 15;
  const int rb = m16 * 16 + ((lane >> 4) << 2);
#pragma unroll
  for (int nt = 0; nt < 4; ++nt) {
    const int col = nh * 64 + nt * 16 + mr;
    float bv = bias[col];
    if (addvec) bv += addvec[col];
    const int cblk = col >> 3, clo = col & 7;
#pragma unroll
    for (int r = 0; r < 4; ++r) {
      const int row = rb + r;
      if (row < 50) {
        float v = fmaxf(acc[nt][r] + bv, 0.0f);
        sOut[row * 128 + ((cblk ^ (row & 15)) << 3) + clo] = __float2bfloat16(v);
      }
    }
  }
}

// ---------------- P-GEMM: P = table @ W_chunk, fp32 out (one-time per launch) ----------
// seg0: i2e (100000 rows, chunk0) -> Pi; seg1: t2e (1000, chunk2) -> Pt; seg2: r2e (6, chunk1) -> Pr
__global__ __launch_bounds__(512) void pgemm_kernel(
    const float* __restrict__ i2e, const float* __restrict__ r2e,
    const float* __restrict__ t2e, const __hip_bfloat16* __restrict__ wprep,
    float* __restrict__ Pi, float* __restrict__ Pt, float* __restrict__ Pr) {
  __shared__ __align__(16) __hip_bfloat16 sW[WCHUNK];
  __shared__ __align__(16) __hip_bfloat16 sA[64 * 128];
  const int tid = threadIdx.x, lane = tid & 63, wid = tid >> 6;
  const int m16 = wid & 3, nh = wid >> 2;
  const int bx = blockIdx.x;
  const float* src; const __hip_bfloat16* W; float* dst; long rows0; int nrows;
  if (bx < 1563)      { src = i2e; W = wprep + 0 * WCHUNK; dst = Pi; rows0 = (long)bx * 64;          nrows = 100000; }
  else if (bx < 1579) { src = t2e; W = wprep + 2 * WCHUNK; dst = Pt; rows0 = (long)(bx - 1563) * 64; nrows = 1000; }
  else                { src = r2e; W = wprep + 1 * WCHUNK; dst = Pr; rows0 = 0;                      nrows = 6; }

#pragma unroll
  for (int i = 0; i < 4; ++i) {
    int g = tid + i * 512;
    __builtin_amdgcn_global_load_lds(
        (__attribute__((address_space(1))) void*)(void*)(W + g * 8),
        (__attribute__((address_space(3))) void*)(void*)(sW + g * 8), 16, 0, 0);
  }
  const float4* s4 = (const float4*)src;
#pragma unroll
  for (int i = 0; i < 2; ++i) {
    int g = tid + i * 512;   // 64 rows x 16 kb
    int row = g >> 4, kb = g & 15;
    float4 v0 = {0.f, 0.f, 0.f, 0.f}, v1 = {0.f, 0.f, 0.f, 0.f};
    if (rows0 + row < nrows) {
      long base = (rows0 + row) * 32 + kb * 2;
      v0 = s4[base]; v1 = s4[base + 1];
    }
    uint4 pk;
    pk.x = ((unsigned)bf_bits(v0.y) << 16) | bf_bits(v0.x);
    pk.y = ((unsigned)bf_bits(v0.w) << 16) | bf_bits(v0.z);
    pk.z = ((unsigned)bf_bits(v1.y) << 16) | bf_bits(v1.x);
    pk.w = ((unsigned)bf_bits(v1.w) << 16) | bf_bits(v1.z);
    *(uint4*)(sA + row * 128 + ((kb ^ (row & 15)) << 3)) = pk;
  }
  __syncthreads();

  f32x4 acc[4];
#pragma unroll
  for (int j = 0; j < 4; ++j) acc[j] = (f32x4){0.f, 0.f, 0.f, 0.f};
  mfma_chunk(sA, sW, acc, m16, nh, lane);

  const int mr = lane & 15;
  const int rb = m16 * 16 + ((lane >> 4) << 2);
#pragma unroll
  for (int nt = 0; nt < 4; ++nt) {
    const int col = nh * 64 + nt * 16 + mr;
#pragma unroll
    for (int r = 0; r < 4; ++r) {
      const int row = rb + r;
      if (rows0 + row < nrows) dst[(rows0 + row) * 128 + col] = acc[nt][r];
    }
  }
}

// ---------------- Pu kernel: Pu = u2e @ att1_w[128:], Pu2 = u2e @ lin_w[:128] ----------
__global__ __launch_bounds__(256) void pu_kernel(const float* __restrict__ u2e,
                                                 const float* __restrict__ att1_w,
                                                 const float* __restrict__ lin_w,
                                                 float* __restrict__ Pu,
                                                 float* __restrict__ Pu2) {
  int idx = blockIdx.x * 256 + threadIdx.x;   // 2 * 1280000 threads
  const int HALF = 10000 * 128;
  bool second = idx >= HALF;
  if (second) idx -= HALF;
  int u = idx >> 7, d = idx & 127;
  const float* urow = u2e + (long)u * 128;
  float s = 0.f;
  if (!second) {
    for (int k = 0; k < 128; ++k) s += urow[k] * att1_w[(128 + k) * 128 + d];
    Pu[idx] = s;
  } else {
    for (int k = 0; k < 128; ++k) s += urow[k] * lin_w[k * 128 + d];
    Pu2[idx] = s;
  }
}

// ---------------- main fused kernel: 1 block = 1 user, 2 blocks/CU ----------------
__global__ __launch_bounds__(512, 4) void graphdec_main(
    const float* __restrict__ Pi, const float* __restrict__ Pt,
    const float* __restrict__ Pr, const float* __restrict__ Pu,
    const float* __restrict__ Pu2,
    const float* __restrict__ ne_b, const float* __restrict__ ne1_b,
    const float* __restrict__ att1_b,
    const float* __restrict__ att3_w, const float* __restrict__ att3_b,
    const float* __restrict__ att2_b,
    const float* __restrict__ lin_w, const float* __restrict__ lin_b,
    const float* __restrict__ w1_w, const float* __restrict__ w1_b,
    const float* __restrict__ bn1_g, const float* __restrict__ bn1_b,
    const float* __restrict__ bn1_m, const float* __restrict__ bn1_v,
    const float* __restrict__ w2_w, const float* __restrict__ w2_b,
    const float* __restrict__ bn2_g, const float* __restrict__ bn2_b,
    const float* __restrict__ bn2_m, const float* __restrict__ bn2_v,
    const float* __restrict__ w3_w, const float* __restrict__ w3_b,
    const int* __restrict__ user_idx, const int* __restrict__ item_idx,
    const int* __restrict__ rat_idx, const int* __restrict__ time_idx,
    const __hip_bfloat16* __restrict__ wprep, float* __restrict__ out) {
  __shared__ __align__(16) unsigned char smem[SMEM_TOTAL];
  __hip_bfloat16* sW = (__hip_bfloat16*)(smem + W_OFF);
  __hip_bfloat16* sA = (__hip_bfloat16*)(smem + A_OFF);
  __hip_bfloat16* sB = (__hip_bfloat16*)(smem + B_OFF);
  __hip_bfloat16* sX = (__hip_bfloat16*)(smem + X_OFF);
  float* sAtt3  = (float*)(smem + SMALL);          // 128
  int*   sIdx   = (int*)  (smem + SMALL + 512);    // 192
  float* sUatt  = (float*)(smem + SMALL + 1280);   // 128
  float* sUlin  = (float*)(smem + SMALL + 1792);   // 128
  float* sLogit = (float*)(smem + SMALL + 2304);   // 64
  float* sAtt   = (float*)(smem + SMALL + 2560);   // 64
  float* sPooled= (float*)(smem + SMALL + 2816);   // 128
  float* sComb  = (float*)(smem + SMALL + 3328);   // 128
  float* sH1    = (float*)(smem + SMALL + 3840);   // 32
  // aliases over dead regions (barrier-separated lifetimes)
  float* sPool4 = (float*)(smem + W_OFF);          // 512 f, after last mfma
  float* sCombP = (float*)(smem + W_OFF + 2048);   // 512 f

  const int tid  = threadIdx.x;
  const int lane = tid & 63;
  const int wid  = tid >> 6;
  const int m16  = wid & 3;
  const int nh   = wid >> 2;
  const int b    = blockIdx.x;

  // ---- preload indices, att3, per-user precomputed vectors ----
  if (tid < 192) {
    int c = tid >> 6, l = tid & 63;
    int v = 0;
    if (l < 50) {
      const int* p = (c == 0) ? item_idx : (c == 1) ? rat_idx : time_idx;
      v = p[b * 50 + l];
    }
    sIdx[tid] = v;
  } else if (tid < 320) {
    sAtt3[tid - 192] = att3_w[tid - 192];
  }
  const int uid = user_idx[b];
  if (tid < 128)      sUatt[tid]       = Pu [(long)uid * 128 + tid];
  else if (tid < 256) sUlin[tid - 128] = Pu2[(long)uid * 128 + (tid - 128)];
  __syncthreads();  // B0

  auto stage = [&](const __hip_bfloat16* __restrict__ src) {
#pragma unroll
    for (int i = 0; i < 4; ++i) {
      int g = tid + i * 512;                // 2048 x 16B = 32 KB
      __builtin_amdgcn_global_load_lds(
          (__attribute__((address_space(1))) void*)(void*)(src + g * 8),
          (__attribute__((address_space(3))) void*)(void*)(sW + g * 8), 16, 0, 0);
    }
  };

  f32x4 acc[4];
  const f32x4 zf = {0.f, 0.f, 0.f, 0.f};
  auto zacc = [&]() {
#pragma unroll
    for (int j = 0; j < 4; ++j) acc[j] = zf;
  };

  // ===== phase 0: stage ne1 weights; x1 = relu(Pi[item]+Pr[rat]+Pt[time]+ne_b) -> sA ====
  stage(wprep + 3 * WCHUNK);
#pragma unroll
  for (int i = 0; i < 2; ++i) {
    int g = tid + i * 512;
    if (g < 832) {                         // 52 rows x 16 kb-blocks of 8 elems
      int row = g >> 4, kb = g & 15;
      uint4 pk = {0u, 0u, 0u, 0u};
      if (row < 50) {
        const float4* pi4 = (const float4*)(Pi + (long)sIdx[row] * 128) + kb * 2;
        const float4* pr4 = (const float4*)(Pr + (long)sIdx[64 + row] * 128) + kb * 2;
        const float4* pt4 = (const float4*)(Pt + (long)sIdx[128 + row] * 128) + kb * 2;
        float4 a0 = pi4[0], a1 = pi4[1];
        float4 r0 = pr4[0], r1 = pr4[1];
        float4 t0 = pt4[0], t1 = pt4[1];
        const float* nb = ne_b + kb * 8;
        float s0 = fmaxf(a0.x + r0.x + t0.x + nb[0], 0.f);
        float s1 = fmaxf(a0.y + r0.y + t0.y + nb[1], 0.f);
        float s2 = fmaxf(a0.z + r0.z + t0.z + nb[2], 0.f);
        float s3 = fmaxf(a0.w + r0.w + t0.w + nb[3], 0.f);
        float s4 = fmaxf(a1.x + r1.x + t1.x + nb[4], 0.f);
        float s5 = fmaxf(a1.y + r1.y + t1.y + nb[5], 0.f);
        float s6 = fmaxf(a1.z + r1.z + t1.z + nb[6], 0.f);
        float s7 = fmaxf(a1.w + r1.w + t1.w + nb[7], 0.f);
        pk.x = ((unsigned)bf_bits(s1) << 16) | bf_bits(s0);
        pk.y = ((unsigned)bf_bits(s3) << 16) | bf_bits(s2);
        pk.z = ((unsigned)bf_bits(s5) << 16) | bf_bits(s4);
        pk.w = ((unsigned)bf_bits(s7) << 16) | bf_bits(s6);
      }
      *(uint4*)(sA + row * 128 + ((kb ^ (row & 15)) << 3)) = pk;
    }
  }
  __syncthreads();  // B1

  // ===== ne1: x = relu(x1 @ ne1_w + b) =====
  zacc();
  mfma_chunk(sA, sW, acc, m16, nh, lane);
  __syncthreads();  // B2 (all sW reads done before restage)
  stage(wprep + 4 * WCHUNK);
  epilogue(acc, ne1_b, nullptr, sX, m16, nh, lane);  // x -> sX
  __syncthreads();  // B3

  // ===== att1: a1 = relu(x @ att1_w[:128] + Pu[u] + b) =====
  zacc();
  mfma_chunk(sX, sW, acc, m16, nh, lane);
  __syncthreads();  // B4
  stage(wprep + 5 * WCHUNK);
  epilogue(acc, att1_b, sUatt, sB, m16, nh, lane);   // a1 -> sB
  __syncthreads();  // B5

  // ===== att2: a2 = relu(a1 @ att2_w + b) =====
  zacc();
  mfma_chunk(sB, sW, acc, m16, nh, lane);
  epilogue(acc, att2_b, nullptr, sA, m16, nh, lane); // a2 -> sA
  __syncthreads();  // B6

  // ===== logits: a2 @ att3 (8 lanes/row, swizzled reads) =====
  {
    int row = tid >> 3, p = tid & 7;
    const int base = row * 128;
    bf16x8 b0 = *(const bf16x8*)(sA + base + (((2 * p) ^ (row & 15)) << 3));
    bf16x8 b1 = *(const bf16x8*)(sA + base + (((2 * p + 1) ^ (row & 15)) << 3));
    float s = 0.f;
#pragma unroll
    for (int j = 0; j < 8; ++j) {
      s += (float)b0[j] * sAtt3[p * 16 + j];
      s += (float)b1[j] * sAtt3[p * 16 + 8 + j];
    }
    s += __shfl_xor(s, 1); s += __shfl_xor(s, 2); s += __shfl_xor(s, 4);
    if (p == 0) sLogit[row] = s + att3_b[0];
  }
  __syncthreads();  // B7

  // ===== softmax over 50 (wave 0) =====
  if (wid == 0) {
    float v = (lane < 50) ? sLogit[lane] : -3.4e38f;
    float m = v;
    for (int off = 32; off > 0; off >>= 1) m = fmaxf(m, __shfl_xor(m, off));
    float e = (lane < 50) ? __expf(v - m) : 0.f;
    float s = e;
    for (int off = 32; off > 0; off >>= 1) s += __shfl_xor(s, off);
    sAtt[lane] = e / s;
  }
  __syncthreads();  // B8

  // ===== pooled partials (4 per d), alias over sW =====
  {
    int q = tid >> 7, d = tid & 127;
    const int cblk = d >> 3, clo = d & 7;
    float s = 0.f;
    for (int l = q; l < 50; l += 4)
      s += sAtt[l] * (float)sX[l * 128 + ((cblk ^ (l & 15)) << 3) + clo];
    sPool4[q * 128 + d] = s;
  }
  __syncthreads();  // B9
  if (tid < 128)
    sPooled[tid] = sPool4[tid] + sPool4[128 + tid] + sPool4[256 + tid] + sPool4[384 + tid];
  __syncthreads();  // B10

  // ===== comb = relu(Pu2[u] + pooled @ lin_w[128:] + lin_b), 4 k-partials =====
  {
    int q = tid >> 7, d = tid & 127;
    float s = 0.f;
    for (int j = q * 32; j < q * 32 + 32; ++j) s += sPooled[j] * lin_w[(128 + j) * 128 + d];
    sCombP[q * 128 + d] = s;
  }
  __syncthreads();  // B11
  if (tid < 128)
    sComb[tid] = fmaxf(sCombP[tid] + sCombP[128 + tid] + sCombP[256 + tid] + sCombP[384 + tid]
                       + sUlin[tid] + lin_b[tid], 0.f);
  __syncthreads();  // B12

  // ===== head entirely in wave 0 =====
  if (wid == 0) {
    if (lane < 32) {
      float s = w1_b[lane];
      for (int k = 0; k < 128; ++k) s += sComb[k] * w1_w[k * 32 + lane];
      s = (s - bn1_m[lane]) * rsqrtf(bn1_v[lane] + 1e-5f) * bn1_g[lane] + bn1_b[lane];
      sH1[lane] = fmaxf(s, 0.f);
    }
    if (lane < 16) {
      float s = w2_b[lane];
      for (int k = 0; k < 32; ++k) s += sH1[k] * w2_w[k * 16 + lane];
      s = (s - bn2_m[lane]) * rsqrtf(bn2_v[lane] + 1e-5f) * bn2_g[lane] + bn2_b[lane];
      float p = fmaxf(s, 0.f) * w3_w[lane];   // relu(h2) then dot w3
      p += __shfl_xor(p, 1); p += __shfl_xor(p, 2);
      p += __shfl_xor(p, 4); p += __shfl_xor(p, 8);
      if (lane == 0) out[b] = p + w3_b[0];
    }
  }
}

extern "C" void kernel_launch(void* const* d_in, const int* in_sizes, int n_in,
                              void* d_out, int out_size, void* d_ws, size_t ws_size,
                              hipStream_t stream) {
  const float* u2e    = (const float*)d_in[0];
  const float* i2e    = (const float*)d_in[1];
  const float* r2e    = (const float*)d_in[2];
  const float* t2e    = (const float*)d_in[3];
  const float* ne_w   = (const float*)d_in[4];
  const float* ne_b   = (const float*)d_in[5];
  const float* ne1_w  = (const float*)d_in[6];
  const float* ne1_b  = (const float*)d_in[7];
  const float* att1_w = (const float*)d_in[8];
  const float* att1_b = (const float*)d_in[9];
  const float* att2_w = (const float*)d_in[10];
  const float* att2_b = (const float*)d_in[11];
  const float* att3_w = (const float*)d_in[12];
  const float* att3_b = (const float*)d_in[13];
  const float* lin_w  = (const float*)d_in[14];
  const float* lin_b  = (const float*)d_in[15];
  const float* w1_w   = (const float*)d_in[16];
  const float* w1_b   = (const float*)d_in[17];
  const float* bn1_g  = (const float*)d_in[18];
  const float* bn1_b  = (const float*)d_in[19];
  const float* bn1_m  = (const float*)d_in[20];
  const float* bn1_v  = (const float*)d_in[21];
  const float* w2_w   = (const float*)d_in[22];
  const float* w2_b   = (const float*)d_in[23];
  const float* bn2_g  = (const float*)d_in[24];
  const float* bn2_b  = (const float*)d_in[25];
  const float* bn2_m  = (const float*)d_in[26];
  const float* bn2_v  = (const float*)d_in[27];
  const float* w3_w   = (const float*)d_in[28];
  const float* w3_b   = (const float*)d_in[29];
  const int* user_idx = (const int*)d_in[30];
  const int* item_idx = (const int*)d_in[31];
  const int* rat_idx  = (const int*)d_in[32];
  const int* time_idx = (const int*)d_in[33];

  char* ws = (char*)d_ws;
  __hip_bfloat16* wprep = (__hip_bfloat16*)(ws + WS_WPREP);
  float* Pi  = (float*)(ws + WS_PI);
  float* Pt  = (float*)(ws + WS_PT);
  float* Pr  = (float*)(ws + WS_PR);
  float* Pu  = (float*)(ws + WS_PU);
  float* Pu2 = (float*)(ws + WS_PU2);
  float* out = (float*)d_out;

  prep_weights_kernel<<<24, dim3(64, 4), 0, stream>>>(ne_w, ne1_w, att1_w, att2_w, wprep);
  pgemm_kernel<<<1580, 512, 0, stream>>>(i2e, r2e, t2e, wprep, Pi, Pt, Pr);
  pu_kernel<<<10000, 256, 0, stream>>>(u2e, att1_w, lin_w, Pu, Pu2);
  graphdec_main<<<4096, 512, 0, stream>>>(
      Pi, Pt, Pr, Pu, Pu2, ne_b, ne1_b, att1_b, att3_w, att3_b, att2_b,
      lin_w, lin_b, w1_w, w1_b, bn1_g, bn1_b, bn1_m, bn1_v, w2_w, w2_b,
      bn2_g, bn2_b, bn2_m, bn2_v, w3_w, w3_b,
      user_idx, item_idx, rat_idx, time_idx, wprep, out);
}

// Round 6
// 269.202 us; speedup vs baseline: 1.3066x; 1.3066x over previous
//
#include <hip/hip_runtime.h>
#include <hip/hip_bf16.h>

typedef __bf16 bf16x8 __attribute__((ext_vector_type(8)));
typedef float  f32x4  __attribute__((ext_vector_type(4)));

// LDS layout (bytes). Activations: 52 rows x 128 bf16, XOR-swizzled 16B k-blocks.
// (mfma reads rows up to 63 -> spill into next region; those rows are masked garbage.)
#define W_OFF 0            // weight chunk: 128n x 128k bf16, swizzled (32768 B)
#define A_OFF 32768        // act buf A: x1 then a1 (13312 B)
#define X_OFF 46080        // act buf X: x, persists to pooling (13312 B)
#define SMALL 59392        // small persistent arrays (4096 B)
#define SMEM_TOTAL 63488
#define WCHUNK 16384       // bf16 elems per weight chunk in global

// ws layout (bytes): wprep(8 chunks) | Pi | Pt | Pr | Pu | Pu2  (~62 MB)
#define WS_WPREP 0
#define WS_PI    262144
#define WS_PT    (WS_PI + 51200000)     // Pi: 100000*128 fp32
#define WS_PR    (WS_PT + 512000)       // Pt: 1000*128 fp32
#define WS_PU    (WS_PR + 3072)         // Pr: 6*128 fp32 (ne_b folded in)
#define WS_PU2   (WS_PU + 5120000)      // Pu: 10000*128 fp32

// ---------------- prep: fp32 [k][n] -> bf16 [chunk][n][swizzled k] ----------------
// chunks: 0-2 ne_w slices, 3 ne1_w, 4 att1_w[:128], 5 att2_w, 6 att1_w[128:], 7 lin_w[:128]
__global__ void prep_weights_kernel(const float* __restrict__ ne_w,
                                    const float* __restrict__ ne1_w,
                                    const float* __restrict__ att1_w,
                                    const float* __restrict__ att2_w,
                                    const float* __restrict__ lin_w,
                                    __hip_bfloat16* __restrict__ wout) {
  __shared__ float tile[64][65];
  const int bx = blockIdx.x;
  const int c = bx >> 2, kt = (bx >> 1) & 1, ntile = bx & 1;
  const float* src; int koff;
  if      (c < 3)  { src = ne_w;   koff = c * 128; }
  else if (c == 3) { src = ne1_w;  koff = 0; }
  else if (c == 4) { src = att1_w; koff = 0; }
  else if (c == 5) { src = att2_w; koff = 0; }
  else if (c == 6) { src = att1_w; koff = 128; }
  else             { src = lin_w;  koff = 0; }
  const int tx = threadIdx.x, ty = threadIdx.y;
#pragma unroll
  for (int r = 0; r < 16; ++r) {
    int k = kt * 64 + r * 4 + ty, n = ntile * 64 + tx;
    tile[r * 4 + ty][tx] = src[(koff + k) * 128 + n];   // coalesced over n
  }
  __syncthreads();
#pragma unroll
  for (int r = 0; r < 16; ++r) {
    int n = ntile * 64 + r * 4 + ty, k = kt * 64 + tx;  // chunk-local k in [0,128)
    int off = (c * 128 + n) * 128 + (((k >> 3) ^ (n & 15)) << 3) + (k & 7);
    wout[off] = __float2bfloat16(tile[tx][r * 4 + ty]);
  }
}

// ---------------- helpers ----------------
__device__ __forceinline__ unsigned short bf_bits(float x) {
  return __builtin_bit_cast(unsigned short, __float2bfloat16(x));
}

// A from swizzled act buffer, B from swizzled LDS weight chunk; wave tile 16m x 64n
__device__ __forceinline__ void mfma_chunk(const __hip_bfloat16* sIn,
                                           const __hip_bfloat16* sWl,
                                           f32x4 acc[4], int m16, int nh, int lane) {
  const int mr = lane & 15;
  const int kq = lane >> 4;            // 0..3
  const int arow = (m16 * 16 + mr) * 128;
#pragma unroll
  for (int ks = 0; ks < 4; ++ks) {
    const int swz = (((ks * 4 + kq) ^ mr) << 3);
    bf16x8 a = *(const bf16x8*)(sIn + arow + swz);
#pragma unroll
    for (int nt = 0; nt < 4; ++nt) {
      const int n = nh * 64 + nt * 16 + mr;   // n&15 == mr -> same swz as A
      bf16x8 b = *(const bf16x8*)(sWl + n * 128 + swz);
      acc[nt] = __builtin_amdgcn_mfma_f32_16x16x32_bf16(a, b, acc[nt], 0, 0, 0);
    }
  }
}

// bias + optional row-vector + relu + swizzled bf16 store (rows < 50 only)
__device__ __forceinline__ void epilogue(f32x4 acc[4], const float* __restrict__ bias,
                                         const float* addvec, __hip_bfloat16* sOut,
                                         int m16, int nh, int lane) {
  const int mr = lane & 15;
  const int rb = m16 * 16 + ((lane >> 4) << 2);
#pragma unroll
  for (int nt = 0; nt < 4; ++nt) {
    const int col = nh * 64 + nt * 16 + mr;
    float bv = bias[col];
    if (addvec) bv += addvec[col];
    const int cblk = col >> 3, clo = col & 7;
#pragma unroll
    for (int r = 0; r < 4; ++r) {
      const int row = rb + r;
      if (row < 50) {
        float v = fmaxf(acc[nt][r] + bv, 0.0f);
        sOut[row * 128 + ((cblk ^ (row & 15)) << 3) + clo] = __float2bfloat16(v);
      }
    }
  }
}

// ---------------- P-GEMM: P = table @ W_chunk (+opt bias), fp32 out (once per launch) --
// segs: Pi(i2e,c0) | Pt(t2e,c2) | Pr(r2e,c1,+ne_b) | Pu(u2e,c6) | Pu2(u2e,c7)
__global__ __launch_bounds__(512) void pgemm_kernel(
    const float* __restrict__ i2e, const float* __restrict__ r2e,
    const float* __restrict__ t2e, const float* __restrict__ u2e,
    const float* __restrict__ ne_b, const __hip_bfloat16* __restrict__ wprep,
    float* __restrict__ Pi, float* __restrict__ Pt, float* __restrict__ Pr,
    float* __restrict__ Pu, float* __restrict__ Pu2) {
  __shared__ __align__(16) __hip_bfloat16 sW[WCHUNK];
  __shared__ __align__(16) __hip_bfloat16 sA[64 * 128];
  const int tid = threadIdx.x, lane = tid & 63, wid = tid >> 6;
  const int m16 = wid & 3, nh = wid >> 2;
  const int bx = blockIdx.x;
  const float* src; const __hip_bfloat16* W; float* dst; const float* addb = nullptr;
  long rows0; int nrows;
  if (bx < 1563)      { src = i2e; W = wprep + 0 * WCHUNK; dst = Pi;  rows0 = (long)bx * 64;          nrows = 100000; }
  else if (bx < 1579) { src = t2e; W = wprep + 2 * WCHUNK; dst = Pt;  rows0 = (long)(bx - 1563) * 64; nrows = 1000; }
  else if (bx < 1580) { src = r2e; W = wprep + 1 * WCHUNK; dst = Pr;  rows0 = 0;                      nrows = 6; addb = ne_b; }
  else if (bx < 1737) { src = u2e; W = wprep + 6 * WCHUNK; dst = Pu;  rows0 = (long)(bx - 1580) * 64; nrows = 10000; }
  else                { src = u2e; W = wprep + 7 * WCHUNK; dst = Pu2; rows0 = (long)(bx - 1737) * 64; nrows = 10000; }

#pragma unroll
  for (int i = 0; i < 4; ++i) {
    int g = tid + i * 512;
    __builtin_amdgcn_global_load_lds(
        (__attribute__((address_space(1))) void*)(void*)(W + g * 8),
        (__attribute__((address_space(3))) void*)(void*)(sW + g * 8), 16, 0, 0);
  }
  const float4* s4 = (const float4*)src;
#pragma unroll
  for (int i = 0; i < 2; ++i) {
    int g = tid + i * 512;   // 64 rows x 16 kb
    int row = g >> 4, kb = g & 15;
    float4 v0 = {0.f, 0.f, 0.f, 0.f}, v1 = {0.f, 0.f, 0.f, 0.f};
    if (rows0 + row < nrows) {
      long base = (rows0 + row) * 32 + kb * 2;
      v0 = s4[base]; v1 = s4[base + 1];
    }
    uint4 pk;
    pk.x = ((unsigned)bf_bits(v0.y) << 16) | bf_bits(v0.x);
    pk.y = ((unsigned)bf_bits(v0.w) << 16) | bf_bits(v0.z);
    pk.z = ((unsigned)bf_bits(v1.y) << 16) | bf_bits(v1.x);
    pk.w = ((unsigned)bf_bits(v1.w) << 16) | bf_bits(v1.z);
    *(uint4*)(sA + row * 128 + ((kb ^ (row & 15)) << 3)) = pk;
  }
  __syncthreads();

  f32x4 acc[4];
#pragma unroll
  for (int j = 0; j < 4; ++j) acc[j] = (f32x4){0.f, 0.f, 0.f, 0.f};
  mfma_chunk(sA, sW, acc, m16, nh, lane);

  const int mr = lane & 15;
  const int rb = m16 * 16 + ((lane >> 4) << 2);
#pragma unroll
  for (int nt = 0; nt < 4; ++nt) {
    const int col = nh * 64 + nt * 16 + mr;
    const float bv = addb ? addb[col] : 0.f;
#pragma unroll
    for (int r = 0; r < 4; ++r) {
      const int row = rb + r;
      if (rows0 + row < nrows) dst[(rows0 + row) * 128 + col] = acc[nt][r] + bv;
    }
  }
}

// ---------------- main fused kernel: 1 block = 1 user, 2 blocks/CU ----------------
__global__ __launch_bounds__(512, 4) void graphdec_main(
    const float* __restrict__ Pi, const float* __restrict__ Pt,
    const float* __restrict__ Pr, const float* __restrict__ Pu,
    const float* __restrict__ Pu2,
    const float* __restrict__ ne1_b, const float* __restrict__ att1_b,
    const float* __restrict__ att2_b, const float* __restrict__ att3_w,
    const float* __restrict__ lin_w, const float* __restrict__ lin_b,
    const float* __restrict__ w1_w, const float* __restrict__ w1_b,
    const float* __restrict__ bn1_g, const float* __restrict__ bn1_b,
    const float* __restrict__ bn1_m, const float* __restrict__ bn1_v,
    const float* __restrict__ w2_w, const float* __restrict__ w2_b,
    const float* __restrict__ bn2_g, const float* __restrict__ bn2_b,
    const float* __restrict__ bn2_m, const float* __restrict__ bn2_v,
    const float* __restrict__ w3_w, const float* __restrict__ w3_b,
    const int* __restrict__ user_idx, const int* __restrict__ item_idx,
    const int* __restrict__ rat_idx, const int* __restrict__ time_idx,
    const __hip_bfloat16* __restrict__ wprep, float* __restrict__ out) {
  __shared__ __align__(16) unsigned char smem[SMEM_TOTAL];
  __hip_bfloat16* sW = (__hip_bfloat16*)(smem + W_OFF);
  __hip_bfloat16* sA = (__hip_bfloat16*)(smem + A_OFF);
  __hip_bfloat16* sX = (__hip_bfloat16*)(smem + X_OFF);
  int*   sIdx   = (int*)  (smem + SMALL);          //  0..768   (192)
  float* sUatt  = (float*)(smem + SMALL + 768);    //  128 f
  float* sUlin  = (float*)(smem + SMALL + 1280);   //  128 f
  float* sLP0   = (float*)(smem + SMALL + 1792);   //  64 f (logit partial nh=0)
  float* sLP1   = (float*)(smem + SMALL + 2048);   //  64 f (nh=1)
  float* sAtt   = (float*)(smem + SMALL + 2304);   //  64 f
  float* sPooled= (float*)(smem + SMALL + 2560);   //  128 f
  float* sComb  = (float*)(smem + SMALL + 3072);   //  128 f
  float* sH1    = (float*)(smem + SMALL + 3584);   //  32 f
  // aliases over dead sW (after last mfma; barrier-separated)
  float* sPool4 = (float*)(smem + W_OFF);          // 512 f
  float* sCombP = (float*)(smem + W_OFF + 2048);   // 512 f

  const int tid  = threadIdx.x;
  const int lane = tid & 63;
  const int wid  = tid >> 6;
  const int m16  = wid & 3;
  const int nh   = wid >> 2;
  const int b    = blockIdx.x;

  // ---- per-lane att3 fragment (cols this lane owns in C-layout) ----
  float att3r[4];
#pragma unroll
  for (int nt = 0; nt < 4; ++nt) att3r[nt] = att3_w[nh * 64 + nt * 16 + (lane & 15)];

  // ---- preload indices + per-user precomputed vectors ----
  if (tid < 192) {
    int c = tid >> 6, l = tid & 63;
    int v = 0;
    if (l < 50) {
      const int* p = (c == 0) ? item_idx : (c == 1) ? rat_idx : time_idx;
      v = p[b * 50 + l];
    }
    sIdx[tid] = v;
  }
  const int uid = user_idx[b];
  if (tid >= 256 && tid < 384)      sUatt[tid - 256] = Pu [(long)uid * 128 + (tid - 256)];
  else if (tid >= 384)              sUlin[tid - 384] = Pu2[(long)uid * 128 + (tid - 384)];
  __syncthreads();  // B0

  auto stage = [&](const __hip_bfloat16* __restrict__ src) {
#pragma unroll
    for (int i = 0; i < 4; ++i) {
      int g = tid + i * 512;                // 2048 x 16B = 32 KB
      __builtin_amdgcn_global_load_lds(
          (__attribute__((address_space(1))) void*)(void*)(src + g * 8),
          (__attribute__((address_space(3))) void*)(void*)(sW + g * 8), 16, 0, 0);
    }
  };

  f32x4 acc[4];
  const f32x4 zf = {0.f, 0.f, 0.f, 0.f};
  auto zacc = [&]() {
#pragma unroll
    for (int j = 0; j < 4; ++j) acc[j] = zf;
  };

  // ===== phase 0: stage ne1 weights; x1 = relu(Pi[item]+Pr'[rat]+Pt[time]) -> sA =====
  stage(wprep + 3 * WCHUNK);
#pragma unroll
  for (int i = 0; i < 2; ++i) {
    int g = tid + i * 512;
    if (g < 832) {                         // 52 rows x 16 kb-blocks of 8 elems
      int row = g >> 4, kb = g & 15;
      uint4 pk = {0u, 0u, 0u, 0u};
      if (row < 50) {
        const float4* pi4 = (const float4*)(Pi + (long)sIdx[row] * 128) + kb * 2;
        const float4* pr4 = (const float4*)(Pr + (long)sIdx[64 + row] * 128) + kb * 2;
        const float4* pt4 = (const float4*)(Pt + (long)sIdx[128 + row] * 128) + kb * 2;
        float4 a0 = pi4[0], a1 = pi4[1];
        float4 r0 = pr4[0], r1 = pr4[1];
        float4 t0 = pt4[0], t1 = pt4[1];
        float s0 = fmaxf(a0.x + r0.x + t0.x, 0.f);
        float s1 = fmaxf(a0.y + r0.y + t0.y, 0.f);
        float s2 = fmaxf(a0.z + r0.z + t0.z, 0.f);
        float s3 = fmaxf(a0.w + r0.w + t0.w, 0.f);
        float s4 = fmaxf(a1.x + r1.x + t1.x, 0.f);
        float s5 = fmaxf(a1.y + r1.y + t1.y, 0.f);
        float s6 = fmaxf(a1.z + r1.z + t1.z, 0.f);
        float s7 = fmaxf(a1.w + r1.w + t1.w, 0.f);
        pk.x = ((unsigned)bf_bits(s1) << 16) | bf_bits(s0);
        pk.y = ((unsigned)bf_bits(s3) << 16) | bf_bits(s2);
        pk.z = ((unsigned)bf_bits(s5) << 16) | bf_bits(s4);
        pk.w = ((unsigned)bf_bits(s7) << 16) | bf_bits(s6);
      }
      *(uint4*)(sA + row * 128 + ((kb ^ (row & 15)) << 3)) = pk;
    }
  }
  __syncthreads();  // B1

  // ===== ne1: x = relu(x1 @ ne1_w + b) =====
  zacc();
  mfma_chunk(sA, sW, acc, m16, nh, lane);
  __syncthreads();  // B2 (all sW/sA reads done)
  stage(wprep + 4 * WCHUNK);
  epilogue(acc, ne1_b, nullptr, sX, m16, nh, lane);  // x -> sX
  __syncthreads();  // B3

  // ===== att1: a1 = relu(x @ att1_w[:128] + Pu[u] + b) =====
  zacc();
  mfma_chunk(sX, sW, acc, m16, nh, lane);
  __syncthreads();  // B4
  stage(wprep + 5 * WCHUNK);
  epilogue(acc, att1_b, sUatt, sA, m16, nh, lane);   // a1 -> sA
  __syncthreads();  // B5

  // ===== att2 + in-register logits: logit[row] = sum_col relu(acc+b2[col])*att3[col] =====
  zacc();
  mfma_chunk(sA, sW, acc, m16, nh, lane);
  {
    float lp[4] = {0.f, 0.f, 0.f, 0.f};
#pragma unroll
    for (int nt = 0; nt < 4; ++nt) {
      const int col = nh * 64 + nt * 16 + (lane & 15);
      const float b2 = att2_b[col];
#pragma unroll
      for (int r = 0; r < 4; ++r)
        lp[r] += fmaxf(acc[nt][r] + b2, 0.f) * att3r[nt];
    }
#pragma unroll
    for (int off = 1; off < 16; off <<= 1) {
#pragma unroll
      for (int r = 0; r < 4; ++r) lp[r] += __shfl_xor(lp[r], off);
    }
    if ((lane & 15) == 0) {
      const int rowb = m16 * 16 + ((lane >> 4) << 2);
      float* dst = nh ? sLP1 : sLP0;
#pragma unroll
      for (int r = 0; r < 4; ++r) dst[rowb + r] = lp[r];
    }
  }
  __syncthreads();  // B6

  // ===== softmax over 50 (wave 0; att3_b cancels under softmax) =====
  if (wid == 0) {
    float v = (lane < 50) ? (sLP0[lane] + sLP1[lane]) : -3.4e38f;
    float m = v;
    for (int off = 32; off > 0; off >>= 1) m = fmaxf(m, __shfl_xor(m, off));
    float e = (lane < 50) ? __expf(v - m) : 0.f;
    float s = e;
    for (int off = 32; off > 0; off >>= 1) s += __shfl_xor(s, off);
    sAtt[lane] = e / s;
  }
  __syncthreads();  // B7

  // ===== pooled partials (4 per d), alias over dead sW =====
  {
    int q = tid >> 7, d = tid & 127;
    const int cblk = d >> 3, clo = d & 7;
    float s = 0.f;
    for (int l = q; l < 50; l += 4)
      s += sAtt[l] * (float)sX[l * 128 + ((cblk ^ (l & 15)) << 3) + clo];
    sPool4[q * 128 + d] = s;
  }
  __syncthreads();  // B8
  if (tid < 128)
    sPooled[tid] = sPool4[tid] + sPool4[128 + tid] + sPool4[256 + tid] + sPool4[384 + tid];
  __syncthreads();  // B9

  // ===== comb = relu(Pu2[u] + pooled @ lin_w[128:] + lin_b), 4 k-partials =====
  {
    int q = tid >> 7, d = tid & 127;
    float s = 0.f;
    for (int j = q * 32; j < q * 32 + 32; ++j) s += sPooled[j] * lin_w[(128 + j) * 128 + d];
    sCombP[q * 128 + d] = s;
  }
  __syncthreads();  // B10
  if (tid < 128)
    sComb[tid] = fmaxf(sCombP[tid] + sCombP[128 + tid] + sCombP[256 + tid] + sCombP[384 + tid]
                       + sUlin[tid] + lin_b[tid], 0.f);
  __syncthreads();  // B11

  // ===== head entirely in wave 0 =====
  if (wid == 0) {
    if (lane < 32) {
      float s = w1_b[lane];
      for (int k = 0; k < 128; ++k) s += sComb[k] * w1_w[k * 32 + lane];
      s = (s - bn1_m[lane]) * rsqrtf(bn1_v[lane] + 1e-5f) * bn1_g[lane] + bn1_b[lane];
      sH1[lane] = fmaxf(s, 0.f);
    }
    if (lane < 16) {
      float s = w2_b[lane];
      for (int k = 0; k < 32; ++k) s += sH1[k] * w2_w[k * 16 + lane];
      s = (s - bn2_m[lane]) * rsqrtf(bn2_v[lane] + 1e-5f) * bn2_g[lane] + bn2_b[lane];
      float p = fmaxf(s, 0.f) * w3_w[lane];   // relu(h2) then dot w3
      p += __shfl_xor(p, 1); p += __shfl_xor(p, 2);
      p += __shfl_xor(p, 4); p += __shfl_xor(p, 8);
      if (lane == 0) out[b] = p + w3_b[0];
    }
  }
}

extern "C" void kernel_launch(void* const* d_in, const int* in_sizes, int n_in,
                              void* d_out, int out_size, void* d_ws, size_t ws_size,
                              hipStream_t stream) {
  const float* u2e    = (const float*)d_in[0];
  const float* i2e    = (const float*)d_in[1];
  const float* r2e    = (const float*)d_in[2];
  const float* t2e    = (const float*)d_in[3];
  const float* ne_w   = (const float*)d_in[4];
  const float* ne_b   = (const float*)d_in[5];
  const float* ne1_w  = (const float*)d_in[6];
  const float* ne1_b  = (const float*)d_in[7];
  const float* att1_w = (const float*)d_in[8];
  const float* att1_b = (const float*)d_in[9];
  const float* att2_w = (const float*)d_in[10];
  const float* att2_b = (const float*)d_in[11];
  const float* att3_w = (const float*)d_in[12];
  const float* att3_b = (const float*)d_in[13];
  const float* lin_w  = (const float*)d_in[14];
  const float* lin_b  = (const float*)d_in[15];
  const float* w1_w   = (const float*)d_in[16];
  const float* w1_b   = (const float*)d_in[17];
  const float* bn1_g  = (const float*)d_in[18];
  const float* bn1_b  = (const float*)d_in[19];
  const float* bn1_m  = (const float*)d_in[20];
  const float* bn1_v  = (const float*)d_in[21];
  const float* w2_w   = (const float*)d_in[22];
  const float* w2_b   = (const float*)d_in[23];
  const float* bn2_g  = (const float*)d_in[24];
  const float* bn2_b  = (const float*)d_in[25];
  const float* bn2_m  = (const float*)d_in[26];
  const float* bn2_v  = (const float*)d_in[27];
  const float* w3_w   = (const float*)d_in[28];
  const float* w3_b   = (const float*)d_in[29];
  const int* user_idx = (const int*)d_in[30];
  const int* item_idx = (const int*)d_in[31];
  const int* rat_idx  = (const int*)d_in[32];
  const int* time_idx = (const int*)d_in[33];
  (void)att3_b;  // constant shift under softmax — cancels

  char* ws = (char*)d_ws;
  __hip_bfloat16* wprep = (__hip_bfloat16*)(ws + WS_WPREP);
  float* Pi  = (float*)(ws + WS_PI);
  float* Pt  = (float*)(ws + WS_PT);
  float* Pr  = (float*)(ws + WS_PR);
  float* Pu  = (float*)(ws + WS_PU);
  float* Pu2 = (float*)(ws + WS_PU2);
  float* out = (float*)d_out;

  prep_weights_kernel<<<32, dim3(64, 4), 0, stream>>>(ne_w, ne1_w, att1_w, att2_w,
                                                      lin_w, wprep);
  pgemm_kernel<<<1894, 512, 0, stream>>>(i2e, r2e, t2e, u2e, ne_b, wprep,
                                         Pi, Pt, Pr, Pu, Pu2);
  graphdec_main<<<4096, 512, 0, stream>>>(
      Pi, Pt, Pr, Pu, Pu2, ne1_b, att1_b, att2_b, att3_w,
      lin_w, lin_b, w1_w, w1_b, bn1_g, bn1_b, bn1_m, bn1_v, w2_w, w2_b,
      bn2_g, bn2_b, bn2_m, bn2_v, w3_w, w3_b,
      user_idx, item_idx, rat_idx, time_idx, wprep, out);
}

// Round 7
// 245.040 us; speedup vs baseline: 1.4354x; 1.0986x over previous
//
#include <hip/hip_runtime.h>
#include <hip/hip_bf16.h>

typedef __bf16 bf16x8 __attribute__((ext_vector_type(8)));
typedef float  f32x4  __attribute__((ext_vector_type(4)));

// LDS layout (bytes). Activations: 52 rows x 128 bf16, XOR-swizzled 16B k-blocks.
// mfma A-reads span rows 0..63 -> spill into the next region; spilled rows are
// masked garbage (output rows >= 50 never stored).
#define W_OFF 0            // weight K-half: 128n x 64k bf16, swizzled (16384 B)
#define A_OFF 16384        // act buf A: x1 then a1 (13312 B; read-span 16 KB)
#define X_OFF 29696        // act buf X: x, persists to pooling (13312 B)
#define SMALL 43008        // small persistent arrays (4096 B)
#define SMEM_TOTAL 47104   // -> 3 blocks/CU (160 KB / 47.1 KB)
#define WCHUNK 16384       // bf16 elems per full weight chunk in global
#define WHALF  8192        // bf16 elems per K-half

// ws layout (bytes): wprep(8 chunks) | Pi(bf16) | Pt | Pr | Pu | Pu2  (~36.6 MB)
#define WS_WPREP 0
#define WS_PI    262144
#define WS_PT    (WS_PI + 25600000)     // Pi: 100000*128 bf16
#define WS_PR    (WS_PT + 512000)       // Pt: 1000*128 fp32
#define WS_PU    (WS_PR + 3072)         // Pr: 6*128 fp32 (ne_b folded in)
#define WS_PU2   (WS_PU + 5120000)      // Pu: 10000*128 fp32

// ---------------- prep: fp32 [k][n] -> bf16 [chunk][khalf][n][swizzled k64] ----------
// chunks: 0-2 ne_w slices, 3 ne1_w, 4 att1_w[:128], 5 att2_w, 6 att1_w[128:], 7 lin_w[:128]
__global__ void prep_weights_kernel(const float* __restrict__ ne_w,
                                    const float* __restrict__ ne1_w,
                                    const float* __restrict__ att1_w,
                                    const float* __restrict__ att2_w,
                                    const float* __restrict__ lin_w,
                                    __hip_bfloat16* __restrict__ wout) {
  __shared__ float tile[64][65];
  const int bx = blockIdx.x;
  const int c = bx >> 2, kt = (bx >> 1) & 1, ntile = bx & 1;
  const float* src; int koff;
  if      (c < 3)  { src = ne_w;   koff = c * 128; }
  else if (c == 3) { src = ne1_w;  koff = 0; }
  else if (c == 4) { src = att1_w; koff = 0; }
  else if (c == 5) { src = att2_w; koff = 0; }
  else if (c == 6) { src = att1_w; koff = 128; }
  else             { src = lin_w;  koff = 0; }
  const int tx = threadIdx.x, ty = threadIdx.y;
#pragma unroll
  for (int r = 0; r < 16; ++r) {
    int k = kt * 64 + r * 4 + ty, n = ntile * 64 + tx;
    tile[r * 4 + ty][tx] = src[(koff + k) * 128 + n];   // coalesced over n
  }
  __syncthreads();
#pragma unroll
  for (int r = 0; r < 16; ++r) {
    int n = ntile * 64 + r * 4 + ty, k = kt * 64 + tx;  // chunk-local k in [0,128)
    int h = k >> 6, k64 = k & 63;
    int off = c * WCHUNK + h * WHALF + n * 64 + ((((k64 >> 3) ^ (n & 7))) << 3) + (k64 & 7);
    wout[off] = __float2bfloat16(tile[tx][r * 4 + ty]);
  }
}

// ---------------- helpers ----------------
__device__ __forceinline__ unsigned short bf_bits(float x) {
  return __builtin_bit_cast(unsigned short, __float2bfloat16(x));
}

// One K-half (64) of a 128-K GEMM. A from 16-blk-swizzled act buffer (full-K rows),
// B from 8-blk-swizzled LDS half-chunk. Wave tile 16m x 64n.
__device__ __forceinline__ void mfma_half(const __hip_bfloat16* sIn,
                                          const __hip_bfloat16* sWh,
                                          f32x4 acc[4], int h, int m16, int nh, int lane) {
  const int mr = lane & 15;
  const int kq = lane >> 4;            // 0..3
  const int arow = (m16 * 16 + mr) * 128;
#pragma unroll
  for (int ks = 0; ks < 2; ++ks) {
    const int kb16 = h * 8 + ks * 4 + kq;           // logical 16B-block in full K
    bf16x8 a = *(const bf16x8*)(sIn + arow + ((kb16 ^ mr) << 3));
    const int swzb = (((ks * 4 + kq) ^ (mr & 7)) << 3);
#pragma unroll
    for (int nt = 0; nt < 4; ++nt) {
      const int n = nh * 64 + nt * 16 + mr;         // n&7 == mr&7 -> swzb valid
      bf16x8 b = *(const bf16x8*)(sWh + n * 64 + swzb);
      acc[nt] = __builtin_amdgcn_mfma_f32_16x16x32_bf16(a, b, acc[nt], 0, 0, 0);
    }
  }
}

// bias + optional row-vector + relu + swizzled bf16 store (rows < 50 only)
__device__ __forceinline__ void epilogue(f32x4 acc[4], const float* __restrict__ bias,
                                         const float* addvec, __hip_bfloat16* sOut,
                                         int m16, int nh, int lane) {
  const int mr = lane & 15;
  const int rb = m16 * 16 + ((lane >> 4) << 2);
#pragma unroll
  for (int nt = 0; nt < 4; ++nt) {
    const int col = nh * 64 + nt * 16 + mr;
    float bv = bias[col];
    if (addvec) bv += addvec[col];
    const int cblk = col >> 3, clo = col & 7;
#pragma unroll
    for (int r = 0; r < 4; ++r) {
      const int row = rb + r;
      if (row < 50) {
        float v = fmaxf(acc[nt][r] + bv, 0.0f);
        sOut[row * 128 + ((cblk ^ (row & 15)) << 3) + clo] = __float2bfloat16(v);
      }
    }
  }
}

// ---------------- P-GEMM: P = table @ W_chunk (+opt bias), once per launch ----------
// segs: Pi(i2e,c0,bf16 out) | Pt(t2e,c2) | Pr(r2e,c1,+ne_b) | Pu(u2e,c6) | Pu2(u2e,c7)
__global__ __launch_bounds__(512) void pgemm_kernel(
    const float* __restrict__ i2e, const float* __restrict__ r2e,
    const float* __restrict__ t2e, const float* __restrict__ u2e,
    const float* __restrict__ ne_b, const __hip_bfloat16* __restrict__ wprep,
    __hip_bfloat16* __restrict__ Pi, float* __restrict__ Pt, float* __restrict__ Pr,
    float* __restrict__ Pu, float* __restrict__ Pu2) {
  __shared__ __align__(16) __hip_bfloat16 sW[WCHUNK];
  __shared__ __align__(16) __hip_bfloat16 sA[64 * 128];
  const int tid = threadIdx.x, lane = tid & 63, wid = tid >> 6;
  const int m16 = wid & 3, nh = wid >> 2;
  const int bx = blockIdx.x;
  const float* src; const __hip_bfloat16* W; float* dst = nullptr;
  const float* addb = nullptr; bool bf_out = false;
  long rows0; int nrows;
  if (bx < 1563)      { src = i2e; W = wprep + 0 * WCHUNK; bf_out = true; rows0 = (long)bx * 64;          nrows = 100000; }
  else if (bx < 1579) { src = t2e; W = wprep + 2 * WCHUNK; dst = Pt;  rows0 = (long)(bx - 1563) * 64; nrows = 1000; }
  else if (bx < 1580) { src = r2e; W = wprep + 1 * WCHUNK; dst = Pr;  rows0 = 0;                      nrows = 6; addb = ne_b; }
  else if (bx < 1737) { src = u2e; W = wprep + 6 * WCHUNK; dst = Pu;  rows0 = (long)(bx - 1580) * 64; nrows = 10000; }
  else                { src = u2e; W = wprep + 7 * WCHUNK; dst = Pu2; rows0 = (long)(bx - 1737) * 64; nrows = 10000; }

#pragma unroll
  for (int i = 0; i < 4; ++i) {
    int g = tid + i * 512;
    __builtin_amdgcn_global_load_lds(
        (__attribute__((address_space(1))) void*)(void*)(W + g * 8),
        (__attribute__((address_space(3))) void*)(void*)(sW + g * 8), 16, 0, 0);
  }
  const float4* s4 = (const float4*)src;
#pragma unroll
  for (int i = 0; i < 2; ++i) {
    int g = tid + i * 512;   // 64 rows x 16 kb
    int row = g >> 4, kb = g & 15;
    float4 v0 = {0.f, 0.f, 0.f, 0.f}, v1 = {0.f, 0.f, 0.f, 0.f};
    if (rows0 + row < nrows) {
      long base = (rows0 + row) * 32 + kb * 2;
      v0 = s4[base]; v1 = s4[base + 1];
    }
    uint4 pk;
    pk.x = ((unsigned)bf_bits(v0.y) << 16) | bf_bits(v0.x);
    pk.y = ((unsigned)bf_bits(v0.w) << 16) | bf_bits(v0.z);
    pk.z = ((unsigned)bf_bits(v1.y) << 16) | bf_bits(v1.x);
    pk.w = ((unsigned)bf_bits(v1.w) << 16) | bf_bits(v1.z);
    *(uint4*)(sA + row * 128 + ((kb ^ (row & 15)) << 3)) = pk;
  }
  __syncthreads();

  f32x4 acc[4];
#pragma unroll
  for (int j = 0; j < 4; ++j) acc[j] = (f32x4){0.f, 0.f, 0.f, 0.f};
  mfma_half(sA, sW, acc, 0, m16, nh, lane);
  mfma_half(sA, sW + WHALF, acc, 1, m16, nh, lane);

  const int mr = lane & 15;
  const int rb = m16 * 16 + ((lane >> 4) << 2);
#pragma unroll
  for (int nt = 0; nt < 4; ++nt) {
    const int col = nh * 64 + nt * 16 + mr;
    const float bv = addb ? addb[col] : 0.f;
#pragma unroll
    for (int r = 0; r < 4; ++r) {
      const int row = rb + r;
      if (rows0 + row < nrows) {
        if (bf_out) Pi[(rows0 + row) * 128 + col] = __float2bfloat16(acc[nt][r]);
        else        dst[(rows0 + row) * 128 + col] = acc[nt][r] + bv;
      }
    }
  }
}

// ---------------- main fused kernel: 1 block = 1 user, 3 blocks/CU ----------------
__global__ __launch_bounds__(512, 6) void graphdec_main(
    const __hip_bfloat16* __restrict__ Pi, const float* __restrict__ Pt,
    const float* __restrict__ Pr, const float* __restrict__ Pu,
    const float* __restrict__ Pu2,
    const float* __restrict__ ne1_b, const float* __restrict__ att1_b,
    const float* __restrict__ att2_b, const float* __restrict__ att3_w,
    const float* __restrict__ lin_w, const float* __restrict__ lin_b,
    const float* __restrict__ w1_w, const float* __restrict__ w1_b,
    const float* __restrict__ bn1_g, const float* __restrict__ bn1_b,
    const float* __restrict__ bn1_m, const float* __restrict__ bn1_v,
    const float* __restrict__ w2_w, const float* __restrict__ w2_b,
    const float* __restrict__ bn2_g, const float* __restrict__ bn2_b,
    const float* __restrict__ bn2_m, const float* __restrict__ bn2_v,
    const float* __restrict__ w3_w, const float* __restrict__ w3_b,
    const int* __restrict__ user_idx, const int* __restrict__ item_idx,
    const int* __restrict__ rat_idx, const int* __restrict__ time_idx,
    const __hip_bfloat16* __restrict__ wprep, float* __restrict__ out) {
  __shared__ __align__(16) unsigned char smem[SMEM_TOTAL];
  __hip_bfloat16* sW = (__hip_bfloat16*)(smem + W_OFF);
  __hip_bfloat16* sA = (__hip_bfloat16*)(smem + A_OFF);
  __hip_bfloat16* sX = (__hip_bfloat16*)(smem + X_OFF);
  int*   sIdx   = (int*)  (smem + SMALL);          //  192 ints
  float* sUatt  = (float*)(smem + SMALL + 768);    //  128 f
  float* sUlin  = (float*)(smem + SMALL + 1280);   //  128 f
  float* sLP0   = (float*)(smem + SMALL + 1792);   //  64 f
  float* sLP1   = (float*)(smem + SMALL + 2048);   //  64 f
  float* sAtt   = (float*)(smem + SMALL + 2304);   //  64 f
  float* sPooled= (float*)(smem + SMALL + 2560);   //  128 f
  float* sComb  = (float*)(smem + SMALL + 3072);   //  128 f
  float* sH1    = (float*)(smem + SMALL + 3584);   //  32 f
  // aliases over dead sW (after last mfma; barrier-separated)
  float* sPool4 = (float*)(smem + W_OFF);          // 512 f
  float* sCombP = (float*)(smem + W_OFF + 2048);   // 512 f

  const int tid  = threadIdx.x;
  const int lane = tid & 63;
  const int wid  = tid >> 6;
  const int m16  = wid & 3;
  const int nh   = wid >> 2;
  const int b    = blockIdx.x;

  // ---- per-lane att3 fragment (cols this lane owns in C-layout) ----
  float att3r[4];
#pragma unroll
  for (int nt = 0; nt < 4; ++nt) att3r[nt] = att3_w[nh * 64 + nt * 16 + (lane & 15)];

  // ---- preload indices + per-user precomputed vectors ----
  if (tid < 192) {
    int c = tid >> 6, l = tid & 63;
    int v = 0;
    if (l < 50) {
      const int* p = (c == 0) ? item_idx : (c == 1) ? rat_idx : time_idx;
      v = p[b * 50 + l];
    }
    sIdx[tid] = v;
  }
  const int uid = user_idx[b];
  if (tid >= 256 && tid < 384)      sUatt[tid - 256] = Pu [(long)uid * 128 + (tid - 256)];
  else if (tid >= 384)              sUlin[tid - 384] = Pu2[(long)uid * 128 + (tid - 384)];
  __syncthreads();  // B0

  auto stage16 = [&](const __hip_bfloat16* __restrict__ src) {
#pragma unroll
    for (int i = 0; i < 2; ++i) {
      int g = tid + i * 512;                // 1024 x 16B = 16 KB
      __builtin_amdgcn_global_load_lds(
          (__attribute__((address_space(1))) void*)(void*)(src + g * 8),
          (__attribute__((address_space(3))) void*)(void*)(sW + g * 8), 16, 0, 0);
    }
  };

  f32x4 acc[4];
  const f32x4 zf = {0.f, 0.f, 0.f, 0.f};
  auto zacc = [&]() {
#pragma unroll
    for (int j = 0; j < 4; ++j) acc[j] = zf;
  };

  // ===== phase 0: stage ne1 h0; x1 = relu(Pi[item]+Pr'[rat]+Pt[time]) -> sA =====
  stage16(wprep + 3 * WCHUNK);
#pragma unroll
  for (int i = 0; i < 2; ++i) {
    int g = tid + i * 512;
    if (g < 832) {                         // 52 rows x 16 kb-blocks of 8 elems
      int row = g >> 4, kb = g & 15;
      uint4 pk = {0u, 0u, 0u, 0u};
      if (row < 50) {
        const bf16x8 pv = *(const bf16x8*)(Pi + (long)sIdx[row] * 128 + kb * 8);
        const float4* pr4 = (const float4*)(Pr + (long)sIdx[64 + row] * 128) + kb * 2;
        const float4* pt4 = (const float4*)(Pt + (long)sIdx[128 + row] * 128) + kb * 2;
        float4 r0 = pr4[0], r1 = pr4[1];
        float4 t0 = pt4[0], t1 = pt4[1];
        float s0 = fmaxf((float)pv[0] + r0.x + t0.x, 0.f);
        float s1 = fmaxf((float)pv[1] + r0.y + t0.y, 0.f);
        float s2 = fmaxf((float)pv[2] + r0.z + t0.z, 0.f);
        float s3 = fmaxf((float)pv[3] + r0.w + t0.w, 0.f);
        float s4 = fmaxf((float)pv[4] + r1.x + t1.x, 0.f);
        float s5 = fmaxf((float)pv[5] + r1.y + t1.y, 0.f);
        float s6 = fmaxf((float)pv[6] + r1.z + t1.z, 0.f);
        float s7 = fmaxf((float)pv[7] + r1.w + t1.w, 0.f);
        pk.x = ((unsigned)bf_bits(s1) << 16) | bf_bits(s0);
        pk.y = ((unsigned)bf_bits(s3) << 16) | bf_bits(s2);
        pk.z = ((unsigned)bf_bits(s5) << 16) | bf_bits(s4);
        pk.w = ((unsigned)bf_bits(s7) << 16) | bf_bits(s6);
      }
      *(uint4*)(sA + row * 128 + ((kb ^ (row & 15)) << 3)) = pk;
    }
  }
  __syncthreads();  // B1

  // ===== ne1: x = relu(x1 @ ne1_w + b) =====
  zacc();
  mfma_half(sA, sW, acc, 0, m16, nh, lane);
  __syncthreads();  // B2
  stage16(wprep + 3 * WCHUNK + WHALF);
  __syncthreads();  // B3
  mfma_half(sA, sW, acc, 1, m16, nh, lane);
  __syncthreads();  // B4
  stage16(wprep + 4 * WCHUNK);
  epilogue(acc, ne1_b, nullptr, sX, m16, nh, lane);  // x -> sX
  __syncthreads();  // B5

  // ===== att1: a1 = relu(x @ att1_w[:128] + Pu[u] + b) =====
  zacc();
  mfma_half(sX, sW, acc, 0, m16, nh, lane);
  __syncthreads();  // B6
  stage16(wprep + 4 * WCHUNK + WHALF);
  __syncthreads();  // B7
  mfma_half(sX, sW, acc, 1, m16, nh, lane);
  __syncthreads();  // B8
  stage16(wprep + 5 * WCHUNK);
  epilogue(acc, att1_b, sUatt, sA, m16, nh, lane);   // a1 -> sA
  __syncthreads();  // B9

  // ===== att2 + in-register logits =====
  zacc();
  mfma_half(sA, sW, acc, 0, m16, nh, lane);
  __syncthreads();  // B10
  stage16(wprep + 5 * WCHUNK + WHALF);
  __syncthreads();  // B11
  mfma_half(sA, sW, acc, 1, m16, nh, lane);
  {
    float lp[4] = {0.f, 0.f, 0.f, 0.f};
#pragma unroll
    for (int nt = 0; nt < 4; ++nt) {
      const int col = nh * 64 + nt * 16 + (lane & 15);
      const float b2 = att2_b[col];
#pragma unroll
      for (int r = 0; r < 4; ++r)
        lp[r] += fmaxf(acc[nt][r] + b2, 0.f) * att3r[nt];
    }
#pragma unroll
    for (int off = 1; off < 16; off <<= 1) {
#pragma unroll
      for (int r = 0; r < 4; ++r) lp[r] += __shfl_xor(lp[r], off);
    }
    if ((lane & 15) == 0) {
      const int rowb = m16 * 16 + ((lane >> 4) << 2);
      float* dst = nh ? sLP1 : sLP0;
#pragma unroll
      for (int r = 0; r < 4; ++r) dst[rowb + r] = lp[r];
    }
  }
  __syncthreads();  // B12

  // ===== softmax over 50 (wave 0; att3_b cancels under softmax) =====
  if (wid == 0) {
    float v = (lane < 50) ? (sLP0[lane] + sLP1[lane]) : -3.4e38f;
    float m = v;
    for (int off = 32; off > 0; off >>= 1) m = fmaxf(m, __shfl_xor(m, off));
    float e = (lane < 50) ? __expf(v - m) : 0.f;
    float s = e;
    for (int off = 32; off > 0; off >>= 1) s += __shfl_xor(s, off);
    sAtt[lane] = e / s;
  }
  __syncthreads();  // B13

  // ===== pooled partials (4 per d), alias over dead sW =====
  {
    int q = tid >> 7, d = tid & 127;
    const int cblk = d >> 3, clo = d & 7;
    float s = 0.f;
    for (int l = q; l < 50; l += 4)
      s += sAtt[l] * (float)sX[l * 128 + ((cblk ^ (l & 15)) << 3) + clo];
    sPool4[q * 128 + d] = s;
  }
  __syncthreads();  // B14
  if (tid < 128)
    sPooled[tid] = sPool4[tid] + sPool4[128 + tid] + sPool4[256 + tid] + sPool4[384 + tid];
  __syncthreads();  // B15

  // ===== comb = relu(Pu2[u] + pooled @ lin_w[128:] + lin_b), 4 k-partials =====
  {
    int q = tid >> 7, d = tid & 127;
    float s = 0.f;
    for (int j = q * 32; j < q * 32 + 32; ++j) s += sPooled[j] * lin_w[(128 + j) * 128 + d];
    sCombP[q * 128 + d] = s;
  }
  __syncthreads();  // B16
  if (tid < 128)
    sComb[tid] = fmaxf(sCombP[tid] + sCombP[128 + tid] + sCombP[256 + tid] + sCombP[384 + tid]
                       + sUlin[tid] + lin_b[tid], 0.f);
  __syncthreads();  // B17

  // ===== head entirely in wave 0 =====
  if (wid == 0) {
    if (lane < 32) {
      float s = w1_b[lane];
      for (int k = 0; k < 128; ++k) s += sComb[k] * w1_w[k * 32 + lane];
      s = (s - bn1_m[lane]) * rsqrtf(bn1_v[lane] + 1e-5f) * bn1_g[lane] + bn1_b[lane];
      sH1[lane] = fmaxf(s, 0.f);
    }
    if (lane < 16) {
      float s = w2_b[lane];
      for (int k = 0; k < 32; ++k) s += sH1[k] * w2_w[k * 16 + lane];
      s = (s - bn2_m[lane]) * rsqrtf(bn2_v[lane] + 1e-5f) * bn2_g[lane] + bn2_b[lane];
      float p = fmaxf(s, 0.f) * w3_w[lane];   // relu(h2) then dot w3
      p += __shfl_xor(p, 1); p += __shfl_xor(p, 2);
      p += __shfl_xor(p, 4); p += __shfl_xor(p, 8);
      if (lane == 0) out[b] = p + w3_b[0];
    }
  }
}

extern "C" void kernel_launch(void* const* d_in, const int* in_sizes, int n_in,
                              void* d_out, int out_size, void* d_ws, size_t ws_size,
                              hipStream_t stream) {
  const float* u2e    = (const float*)d_in[0];
  const float* i2e    = (const float*)d_in[1];
  const float* r2e    = (const float*)d_in[2];
  const float* t2e    = (const float*)d_in[3];
  const float* ne_w   = (const float*)d_in[4];
  const float* ne_b   = (const float*)d_in[5];
  const float* ne1_w  = (const float*)d_in[6];
  const float* ne1_b  = (const float*)d_in[7];
  const float* att1_w = (const float*)d_in[8];
  const float* att1_b = (const float*)d_in[9];
  const float* att2_w = (const float*)d_in[10];
  const float* att2_b = (const float*)d_in[11];
  const float* att3_w = (const float*)d_in[12];
  const float* att3_b = (const float*)d_in[13];
  const float* lin_w  = (const float*)d_in[14];
  const float* lin_b  = (const float*)d_in[15];
  const float* w1_w   = (const float*)d_in[16];
  const float* w1_b   = (const float*)d_in[17];
  const float* bn1_g  = (const float*)d_in[18];
  const float* bn1_b  = (const float*)d_in[19];
  const float* bn1_m  = (const float*)d_in[20];
  const float* bn1_v  = (const float*)d_in[21];
  const float* w2_w   = (const float*)d_in[22];
  const float* w2_b   = (const float*)d_in[23];
  const float* bn2_g  = (const float*)d_in[24];
  const float* bn2_b  = (const float*)d_in[25];
  const float* bn2_m  = (const float*)d_in[26];
  const float* bn2_v  = (const float*)d_in[27];
  const float* w3_w   = (const float*)d_in[28];
  const float* w3_b   = (const float*)d_in[29];
  const int* user_idx = (const int*)d_in[30];
  const int* item_idx = (const int*)d_in[31];
  const int* rat_idx  = (const int*)d_in[32];
  const int* time_idx = (const int*)d_in[33];
  (void)att3_b;  // constant shift under softmax — cancels

  char* ws = (char*)d_ws;
  __hip_bfloat16* wprep = (__hip_bfloat16*)(ws + WS_WPREP);
  __hip_bfloat16* Pi = (__hip_bfloat16*)(ws + WS_PI);
  float* Pt  = (float*)(ws + WS_PT);
  float* Pr  = (float*)(ws + WS_PR);
  float* Pu  = (float*)(ws + WS_PU);
  float* Pu2 = (float*)(ws + WS_PU2);
  float* out = (float*)d_out;

  prep_weights_kernel<<<32, dim3(64, 4), 0, stream>>>(ne_w, ne1_w, att1_w, att2_w,
                                                      lin_w, wprep);
  pgemm_kernel<<<1894, 512, 0, stream>>>(i2e, r2e, t2e, u2e, ne_b, wprep,
                                         Pi, Pt, Pr, Pu, Pu2);
  graphdec_main<<<4096, 512, 0, stream>>>(
      Pi, Pt, Pr, Pu, Pu2, ne1_b, att1_b, att2_b, att3_w,
      lin_w, lin_b, w1_w, w1_b, bn1_g, bn1_b, bn1_m, bn1_v, w2_w, w2_b,
      bn2_g, bn2_b, bn2_m, bn2_v, w3_w, w3_b,
      user_idx, item_idx, rat_idx, time_idx, wprep, out);
}